// Round 1
// baseline (2502.172 us; speedup 1.0000x reference)
//
#include <hip/hip_runtime.h>
#include <math.h>

// Problem constants
#define S_ 2048
#define D_ 256
#define B_ 4
#define H_ 4
// M = B*S = 8192, DH = 64, EXPAND*D = 1024

// ---------------------------------------------------------------------------
// BN coefficient precompute: h = x*sc[ch] + bs[ch]
// ---------------------------------------------------------------------------
__global__ __launch_bounds__(256) void bn_coef_k(
    const float* __restrict__ g1, const float* __restrict__ b1,
    const float* __restrict__ m1, const float* __restrict__ v1,
    const float* __restrict__ g2, const float* __restrict__ b2,
    const float* __restrict__ m2, const float* __restrict__ v2,
    float* __restrict__ out)
{
    int i = threadIdx.x;
    float s1 = g1[i] * rsqrtf(v1[i] + 1e-3f);
    out[i]       = s1;
    out[256 + i] = b1[i] - m1[i] * s1;
    float s2 = g2[i] * rsqrtf(v2[i] + 1e-3f);
    out[512 + i] = s2;
    out[768 + i] = b2[i] - m2[i] * s2;
}

// ---------------------------------------------------------------------------
// Fused GEMM: C = post( pre(A) @ W ), 64x64 tile, BK=32, fp32.
// PRE:  0 = none, 1 = BN affine on A columns (sc/bs indexed by k-channel)
// POST: 0 = none, 1 = +res,    2 = swish
// ---------------------------------------------------------------------------
template<int PRE, int POST>
__global__ __launch_bounds__(256) void gemm_k(
    const float* __restrict__ A, const float* __restrict__ W,
    const float* __restrict__ res, float* __restrict__ C,
    int M, int N, int K,
    const float* __restrict__ sc, const float* __restrict__ bs)
{
    __shared__ float As[32][65];   // [k][m] transposed
    __shared__ float Ws[32][65];   // [k][n]
    const int n0 = blockIdx.x * 64;
    const int m0 = blockIdx.y * 64;
    const int t  = threadIdx.x;
    const int tx = t & 15, ty = t >> 4;

    float acc[4][4] = {};

    for (int k0 = 0; k0 < K; k0 += 32) {
        // stage A tile (64 rows x 32 k), fused BN affine, store transposed
        for (int l = t; l < 512; l += 256) {
            int row = l >> 3, c4 = l & 7;
            float4 av = *(const float4*)&A[(size_t)(m0 + row) * K + k0 + c4 * 4];
            float vv[4] = {av.x, av.y, av.z, av.w};
            #pragma unroll
            for (int c = 0; c < 4; ++c) {
                float v = vv[c];
                if (PRE == 1) { int ch = k0 + c4 * 4 + c; v = v * sc[ch] + bs[ch]; }
                As[c4 * 4 + c][row] = v;
            }
        }
        // stage W tile (32 k x 64 n)
        for (int l = t; l < 512; l += 256) {
            int row = l >> 4, c4 = l & 15;
            float4 wv = *(const float4*)&W[(size_t)(k0 + row) * N + n0 + c4 * 4];
            Ws[row][c4 * 4 + 0] = wv.x; Ws[row][c4 * 4 + 1] = wv.y;
            Ws[row][c4 * 4 + 2] = wv.z; Ws[row][c4 * 4 + 3] = wv.w;
        }
        __syncthreads();
        #pragma unroll
        for (int kk = 0; kk < 32; ++kk) {
            float a0 = As[kk][ty * 4 + 0], a1 = As[kk][ty * 4 + 1];
            float a2 = As[kk][ty * 4 + 2], a3 = As[kk][ty * 4 + 3];
            float w0 = Ws[kk][tx * 4 + 0], w1v = Ws[kk][tx * 4 + 1];
            float w2v = Ws[kk][tx * 4 + 2], w3 = Ws[kk][tx * 4 + 3];
            acc[0][0] += a0 * w0; acc[0][1] += a0 * w1v; acc[0][2] += a0 * w2v; acc[0][3] += a0 * w3;
            acc[1][0] += a1 * w0; acc[1][1] += a1 * w1v; acc[1][2] += a1 * w2v; acc[1][3] += a1 * w3;
            acc[2][0] += a2 * w0; acc[2][1] += a2 * w1v; acc[2][2] += a2 * w2v; acc[2][3] += a2 * w3;
            acc[3][0] += a3 * w0; acc[3][1] += a3 * w1v; acc[3][2] += a3 * w2v; acc[3][3] += a3 * w3;
        }
        __syncthreads();
    }

    #pragma unroll
    for (int i = 0; i < 4; ++i) {
        #pragma unroll
        for (int j = 0; j < 4; ++j) {
            int m = m0 + ty * 4 + i, n = n0 + tx * 4 + j;
            float c = acc[i][j];
            if (POST == 1) c += res[(size_t)m * N + n];
            if (POST == 2) c = c / (1.0f + expf(-c));
            C[(size_t)m * N + n] = c;
        }
    }
}

// ---------------------------------------------------------------------------
// Flash-style attention, fp32. One block = one (b,h) x 32-query tile.
// 256 threads = 4 waves; wave g owns query rows g*8..g*8+7; lane = key index /
// output dim. Online softmax with 64-lane shuffle reductions.
// qkv layout: [b*S+s][768], q = h*192+[0,64), k = +64, v = +128.
// Output o layout: [b*S+q][256] at column h*64+d.
// ---------------------------------------------------------------------------
__global__ __launch_bounds__(256) void attn_k(
    const float* __restrict__ qkv, const int* __restrict__ mask,
    float* __restrict__ o)
{
    __shared__ float Qs[32][65];
    __shared__ float Ks[64][65];
    __shared__ float Vs[64][65];
    __shared__ float Ps[32][65];
    __shared__ float mAdd[64];

    const int b = blockIdx.z, h = blockIdx.y;
    const int q0 = blockIdx.x * 32;
    const int t = threadIdx.x;
    const int lane = t & 63, g = t >> 6;

    // load Q tile, pre-scaled by D^-0.5 = 1/16
    for (int l = t; l < 512; l += 256) {
        int r = l >> 4, c4 = l & 15;
        float4 qv = *(const float4*)&qkv[(size_t)(b * S_ + q0 + r) * 768 + h * 192 + c4 * 4];
        Qs[r][c4 * 4 + 0] = qv.x * 0.0625f; Qs[r][c4 * 4 + 1] = qv.y * 0.0625f;
        Qs[r][c4 * 4 + 2] = qv.z * 0.0625f; Qs[r][c4 * 4 + 3] = qv.w * 0.0625f;
    }

    float m_r[8], l_r[8], fac_r[8], O_r[8];
    #pragma unroll
    for (int i = 0; i < 8; ++i) { m_r[i] = -1e30f; l_r[i] = 0.0f; O_r[i] = 0.0f; fac_r[i] = 1.0f; }

    for (int kt = 0; kt < S_ / 64; ++kt) {
        __syncthreads();
        // stage K/V tile (64 keys x 64 dims each)
        for (int l = t; l < 1024; l += 256) {
            int r = l >> 4, c4 = l & 15;
            size_t base = (size_t)(b * S_ + kt * 64 + r) * 768 + h * 192;
            float4 kv = *(const float4*)&qkv[base + 64 + c4 * 4];
            float4 vv = *(const float4*)&qkv[base + 128 + c4 * 4];
            Ks[r][c4 * 4 + 0] = kv.x; Ks[r][c4 * 4 + 1] = kv.y;
            Ks[r][c4 * 4 + 2] = kv.z; Ks[r][c4 * 4 + 3] = kv.w;
            Vs[r][c4 * 4 + 0] = vv.x; Vs[r][c4 * 4 + 1] = vv.y;
            Vs[r][c4 * 4 + 2] = vv.z; Vs[r][c4 * 4 + 3] = vv.w;
        }
        if (t < 64) mAdd[t] = mask[b * S_ + kt * 64 + t] ? 0.0f : -1e9f;
        __syncthreads();

        // scores + online softmax (wave g handles rows g*8+i; lane = key j)
        #pragma unroll
        for (int i = 0; i < 8; ++i) {
            int r = g * 8 + i;
            float s = mAdd[lane];
            #pragma unroll
            for (int d = 0; d < 64; ++d) s += Qs[r][d] * Ks[lane][d];
            float mt = s;
            #pragma unroll
            for (int off = 32; off > 0; off >>= 1) mt = fmaxf(mt, __shfl_xor(mt, off, 64));
            float mnew = fmaxf(m_r[i], mt);
            float f = expf(m_r[i] - mnew);
            float p = expf(s - mnew);
            float ps = p;
            #pragma unroll
            for (int off = 32; off > 0; off >>= 1) ps += __shfl_xor(ps, off, 64);
            l_r[i] = l_r[i] * f + ps;
            m_r[i] = mnew;
            fac_r[i] = f;
            Ps[r][lane] = p;
        }
        __syncthreads();

        // O update: O[r][lane] = O*f + P[r][:] @ V[:][lane]
        #pragma unroll
        for (int i = 0; i < 8; ++i) {
            int r = g * 8 + i;
            float a = 0.0f;
            #pragma unroll
            for (int j = 0; j < 64; ++j) a += Ps[r][j] * Vs[j][lane];
            O_r[i] = O_r[i] * fac_r[i] + a;
        }
    }

    #pragma unroll
    for (int i = 0; i < 8; ++i) {
        int q = q0 + g * 8 + i;
        o[(size_t)(b * S_ + q) * 256 + h * 64 + lane] = O_r[i] / l_r[i];
    }
}

// ---------------------------------------------------------------------------
// Launch
// ---------------------------------------------------------------------------
extern "C" void kernel_launch(void* const* d_in, const int* in_sizes, int n_in,
                              void* d_out, int out_size, void* d_ws, size_t ws_size,
                              hipStream_t stream) {
    const float* x      = (const float*)d_in[0];
    const int*   mask   = (const int*)  d_in[1];
    const float* bn1_g  = (const float*)d_in[2];
    const float* bn1_b  = (const float*)d_in[3];
    const float* bn1_m  = (const float*)d_in[4];
    const float* bn1_v  = (const float*)d_in[5];
    const float* qkv_w  = (const float*)d_in[6];
    const float* proj_w = (const float*)d_in[7];
    const float* bn2_g  = (const float*)d_in[8];
    const float* bn2_b  = (const float*)d_in[9];
    const float* bn2_m  = (const float*)d_in[10];
    const float* bn2_v  = (const float*)d_in[11];
    const float* w1     = (const float*)d_in[12];
    const float* w2     = (const float*)d_in[13];
    float* out = (float*)d_out;

    // workspace layout (floats):
    //   [0, 6291456)          qkv   (8192 x 768)            | reused later
    //   [6291456, 8388608)    o     (8192 x 256)            | by h2 (8192x1024)
    //   [8388608, 10485760)   x2    (8192 x 256)
    //   [10485760, 10486784)  bn coefs (4 x 256)
    float* ws   = (float*)d_ws;
    float* qkv  = ws;
    float* obuf = ws + 6291456;
    float* h2   = ws;              // reuse of qkv+o region (both dead by then)
    float* x2   = ws + 8388608;
    float* bnc  = ws + 10485760;

    const int M = B_ * S_;  // 8192

    bn_coef_k<<<1, 256, 0, stream>>>(bn1_g, bn1_b, bn1_m, bn1_v,
                                     bn2_g, bn2_b, bn2_m, bn2_v, bnc);

    // qkv = BN1(x) @ qkv_w        (8192 x 768 x 256)
    gemm_k<1, 0><<<dim3(768 / 64, M / 64), 256, 0, stream>>>(
        x, qkv_w, nullptr, qkv, M, 768, 256, bnc, bnc + 256);

    // attention -> obuf (B,S,D)
    attn_k<<<dim3(S_ / 32, H_, B_), 256, 0, stream>>>(qkv, mask, obuf);

    // x2 = obuf @ proj_w + x      (8192 x 256 x 256)
    gemm_k<0, 1><<<dim3(256 / 64, M / 64), 256, 0, stream>>>(
        obuf, proj_w, x, x2, M, 256, 256, nullptr, nullptr);

    // h2 = swish(BN2(x2) @ w1)    (8192 x 1024 x 256)
    gemm_k<1, 2><<<dim3(1024 / 64, M / 64), 256, 0, stream>>>(
        x2, w1, nullptr, h2, M, 1024, 256, bnc + 512, bnc + 768);

    // out = h2 @ w2 + x2          (8192 x 256 x 1024)
    gemm_k<0, 1><<<dim3(256 / 64, M / 64), 256, 0, stream>>>(
        h2, w2, x2, out, M, 256, 1024, nullptr, nullptr);
}

// Round 2
// 438.235 us; speedup vs baseline: 5.7097x; 5.7097x over previous
//
#include <hip/hip_runtime.h>
#include <math.h>

// Problem constants
#define S_ 2048
#define D_ 256
#define B_ 4
#define H_ 4
// M = B*S = 8192, DH = 64

typedef __attribute__((ext_vector_type(8))) short  bh8;   // 8 bf16 (4 VGPR)
typedef __attribute__((ext_vector_type(4))) float  fx4;
typedef __attribute__((ext_vector_type(4))) int    ix4;
typedef __attribute__((ext_vector_type(4))) unsigned short us4;
typedef __attribute__((ext_vector_type(4))) unsigned int   ux4;

__device__ inline unsigned short bf16r(float f) {
    unsigned int u = __builtin_bit_cast(unsigned int, f);
    return (unsigned short)((u + 0x7FFFu + ((u >> 16) & 1u)) >> 16);
}
__device__ inline unsigned int pk2(float a, float b) {
    unsigned int ua = __builtin_bit_cast(unsigned int, a);
    unsigned int ub = __builtin_bit_cast(unsigned int, b);
    return ((ua + 0x8000u) >> 16) | ((ub + 0x8000u) & 0xFFFF0000u);
}

// ---------------------------------------------------------------------------
// BN coefficient precompute
// ---------------------------------------------------------------------------
__global__ __launch_bounds__(256) void bn_coef_k(
    const float* __restrict__ g1, const float* __restrict__ b1,
    const float* __restrict__ m1, const float* __restrict__ v1,
    const float* __restrict__ g2, const float* __restrict__ b2,
    const float* __restrict__ m2, const float* __restrict__ v2,
    float* __restrict__ out)
{
    int i = threadIdx.x;
    float s1 = g1[i] * rsqrtf(v1[i] + 1e-3f);
    out[i]       = s1;
    out[256 + i] = b1[i] - m1[i] * s1;
    float s2 = g2[i] * rsqrtf(v2[i] + 1e-3f);
    out[512 + i] = s2;
    out[768 + i] = b2[i] - m2[i] * s2;
}

// ---------------------------------------------------------------------------
// Fused GEMM: C = post( pre(A) @ W ), 64x64 tile, BK=32, fp32 VALU.
// PRE:  0 = none, 1 = BN affine on A columns
// POST: 0 = none, 1 = +res, 2 = swish, 3 = qkv-bf16 epilogue (qkvb + vt)
// ---------------------------------------------------------------------------
template<int PRE, int POST>
__global__ __launch_bounds__(256) void gemm_k(
    const float* __restrict__ A, const float* __restrict__ W,
    const float* __restrict__ res, float* __restrict__ C,
    int M, int N, int K,
    const float* __restrict__ sc, const float* __restrict__ bs,
    unsigned short* __restrict__ qkvb_o, unsigned short* __restrict__ vt_o)
{
    __shared__ float As[32][65];   // [k][m] transposed
    __shared__ float Ws[32][65];   // [k][n]
    const int n0 = blockIdx.x * 64;
    const int m0 = blockIdx.y * 64;
    const int t  = threadIdx.x;
    const int tx = t & 15, ty = t >> 4;

    float acc[4][4] = {};

    for (int k0 = 0; k0 < K; k0 += 32) {
        for (int l = t; l < 512; l += 256) {
            int row = l >> 3, c4 = l & 7;
            float4 av = *(const float4*)&A[(size_t)(m0 + row) * K + k0 + c4 * 4];
            float vv[4] = {av.x, av.y, av.z, av.w};
            #pragma unroll
            for (int c = 0; c < 4; ++c) {
                float v = vv[c];
                if (PRE == 1) { int ch = k0 + c4 * 4 + c; v = v * sc[ch] + bs[ch]; }
                As[c4 * 4 + c][row] = v;
            }
        }
        for (int l = t; l < 512; l += 256) {
            int row = l >> 4, c4 = l & 15;
            float4 wv = *(const float4*)&W[(size_t)(k0 + row) * N + n0 + c4 * 4];
            Ws[row][c4 * 4 + 0] = wv.x; Ws[row][c4 * 4 + 1] = wv.y;
            Ws[row][c4 * 4 + 2] = wv.z; Ws[row][c4 * 4 + 3] = wv.w;
        }
        __syncthreads();
        #pragma unroll
        for (int kk = 0; kk < 32; ++kk) {
            float a0 = As[kk][ty * 4 + 0], a1 = As[kk][ty * 4 + 1];
            float a2 = As[kk][ty * 4 + 2], a3 = As[kk][ty * 4 + 3];
            float w0 = Ws[kk][tx * 4 + 0], w1v = Ws[kk][tx * 4 + 1];
            float w2v = Ws[kk][tx * 4 + 2], w3 = Ws[kk][tx * 4 + 3];
            acc[0][0] += a0 * w0; acc[0][1] += a0 * w1v; acc[0][2] += a0 * w2v; acc[0][3] += a0 * w3;
            acc[1][0] += a1 * w0; acc[1][1] += a1 * w1v; acc[1][2] += a1 * w2v; acc[1][3] += a1 * w3;
            acc[2][0] += a2 * w0; acc[2][1] += a2 * w1v; acc[2][2] += a2 * w2v; acc[2][3] += a2 * w3;
            acc[3][0] += a3 * w0; acc[3][1] += a3 * w1v; acc[3][2] += a3 * w2v; acc[3][3] += a3 * w3;
        }
        __syncthreads();
    }

    if (POST == 3) {
        // qkv epilogue: n-blocks of 64 lie wholly in one region of one head.
        const int h = n0 / 192;
        const int region = (n0 / 64) % 3;   // 0=q, 1=k, 2=v
        #pragma unroll
        for (int i = 0; i < 4; ++i) {
            const int m = m0 + ty * 4 + i;
            if (region < 2) {
                us4 tv;
                #pragma unroll
                for (int j = 0; j < 4; ++j) {
                    float c = acc[i][j];
                    if (region == 0) c *= 0.0625f;   // fold in D^-0.5
                    tv[j] = bf16r(c);
                }
                *(us4*)&qkvb_o[(size_t)m * 512 + h * 128 + region * 64 + tx * 4] = tv;
            } else {
                const int s = m & 2047;
                const size_t vb = ((size_t)(m >> 11) * 4 + h) * 64 + tx * 4;
                #pragma unroll
                for (int j = 0; j < 4; ++j)
                    vt_o[(vb + j) * 2048 + s] = bf16r(acc[i][j]);
            }
        }
        return;
    }

    #pragma unroll
    for (int i = 0; i < 4; ++i) {
        #pragma unroll
        for (int j = 0; j < 4; ++j) {
            int m = m0 + ty * 4 + i, n = n0 + tx * 4 + j;
            float c = acc[i][j];
            if (POST == 1) c += res[(size_t)m * N + n];
            if (POST == 2) c = c / (1.0f + expf(-c));
            C[(size_t)m * N + n] = c;
        }
    }
}

// ---------------------------------------------------------------------------
// MFMA flash attention, bf16 inputs, fp32 accum, NO LDS.
// Block = 4 waves; wave owns 16 q-rows. Grid (S/64, H, B).
// qkvb: [B*S][512] bf16, q at h*128 (pre-scaled by 1/16), k at h*128+64.
// vt:   [B*H][64 d][2048 s] bf16 (V transposed).
// Computes S^T = K·Q^T per 64-key tile (A=K frag, B=Q frag):
//   C layout: col = lane&15 = q, row = (lane>>4)*4+r = key-local.
// Softmax stats per q are in-lane (16 vals) + shfl_xor over lane>>4 groups.
// P^T redistributed to PV B-operand via __shfl; O^T = V^T·P^T accumulated.
// ---------------------------------------------------------------------------
__global__ __launch_bounds__(256) void attn_mfma_k(
    const unsigned short* __restrict__ qkvb,
    const unsigned short* __restrict__ vt,
    const int* __restrict__ mask,
    float* __restrict__ obuf)
{
    const int b = blockIdx.z, h = blockIdx.y;
    const int t = threadIdx.x;
    const int w = t >> 6, lane = t & 63;
    const int g = lane >> 4, qi = lane & 15;
    const int qrow = blockIdx.x * 64 + w * 16;   // seq base of this wave

    // Q B-fragments (col=q=qi, k-dim = d = g*8+j), two 32-d chunks
    bh8 qf0, qf1;
    {
        const unsigned short* qp =
            qkvb + (size_t)(b * 2048 + qrow + qi) * 512 + h * 128 + g * 8;
        qf0 = *(const bh8*)(qp);
        qf1 = *(const bh8*)(qp + 32);
    }

    fx4 o[4];
    #pragma unroll
    for (int dt = 0; dt < 4; ++dt) o[dt] = (fx4){0.f, 0.f, 0.f, 0.f};
    float m_r = -1e30f, l_r = 0.f;

    const unsigned short* kbase =
        qkvb + (size_t)(b * 2048) * 512 + h * 128 + 64 + g * 8;
    const unsigned short* vb0 =
        vt + ((size_t)((b * 4 + h) * 64 + qi)) * 2048 + g * 8;
    const int* mbase = mask + b * 2048 + g * 4;

    for (int k64 = 0; k64 < 2048; k64 += 64) {
        // ---- S^T = K·Q^T over 4 key tiles ----
        fx4 s[4];
        #pragma unroll
        for (int kt = 0; kt < 4; ++kt) {
            const unsigned short* kp = kbase + (size_t)(k64 + kt * 16 + qi) * 512;
            bh8 kf0 = *(const bh8*)(kp);
            bh8 kf1 = *(const bh8*)(kp + 32);
            fx4 z = (fx4){0.f, 0.f, 0.f, 0.f};
            z = __builtin_amdgcn_mfma_f32_16x16x32_bf16(kf0, qf0, z, 0, 0, 0);
            z = __builtin_amdgcn_mfma_f32_16x16x32_bf16(kf1, qf1, z, 0, 0, 0);
            s[kt] = z;
        }
        // ---- mask + row max ----
        float tmax = -1e30f;
        #pragma unroll
        for (int kt = 0; kt < 4; ++kt) {
            ix4 mv = *(const ix4*)(mbase + k64 + kt * 16);
            #pragma unroll
            for (int r = 0; r < 4; ++r) {
                float sv = s[kt][r] + (mv[r] ? 0.0f : -1e9f);
                s[kt][r] = sv;
                tmax = fmaxf(tmax, sv);
            }
        }
        tmax = fmaxf(tmax, __shfl_xor(tmax, 16, 64));
        tmax = fmaxf(tmax, __shfl_xor(tmax, 32, 64));
        float mnew = fmaxf(m_r, tmax);
        float fac = __expf(m_r - mnew);
        // ---- exp + sum + pack to bf16 pairs ----
        float psum = 0.f;
        unsigned int pkv[4][2];
        #pragma unroll
        for (int kt = 0; kt < 4; ++kt) {
            float p0 = __expf(s[kt][0] - mnew);
            float p1 = __expf(s[kt][1] - mnew);
            float p2 = __expf(s[kt][2] - mnew);
            float p3 = __expf(s[kt][3] - mnew);
            psum += (p0 + p1) + (p2 + p3);
            pkv[kt][0] = pk2(p0, p1);
            pkv[kt][1] = pk2(p2, p3);
        }
        psum += __shfl_xor(psum, 16, 64);
        psum += __shfl_xor(psum, 32, 64);
        l_r = l_r * fac + psum;
        m_r = mnew;
        #pragma unroll
        for (int dt = 0; dt < 4; ++dt) {
            o[dt][0] *= fac; o[dt][1] *= fac; o[dt][2] *= fac; o[dt][3] *= fac;
        }
        // ---- PV: O^T += V^T · P^T, two 32-key chunks ----
        #pragma unroll
        for (int c = 0; c < 2; ++c) {
            unsigned int bw[4];
            #pragma unroll
            for (int wd = 0; wd < 4; ++wd) {
                int src = (2 * (g & 1) + (wd >> 1)) * 16 + qi;
                unsigned int va = (unsigned int)__shfl((int)pkv[2 * c][wd & 1], src, 64);
                unsigned int vb = (unsigned int)__shfl((int)pkv[2 * c + 1][wd & 1], src, 64);
                bw[wd] = (g >= 2) ? vb : va;
            }
            ux4 bwv = (ux4){bw[0], bw[1], bw[2], bw[3]};
            bh8 bfrag = __builtin_bit_cast(bh8, bwv);
            #pragma unroll
            for (int dt = 0; dt < 4; ++dt) {
                bh8 af = *(const bh8*)(vb0 + (size_t)dt * 16 * 2048 + k64 + c * 32);
                o[dt] = __builtin_amdgcn_mfma_f32_16x16x32_bf16(af, bfrag, o[dt], 0, 0, 0);
            }
        }
    }

    // ---- epilogue: normalize, store O (lane holds q=qi, d = dt*16+g*4+r) ----
    float inv = 1.0f / l_r;
    float* op = obuf + (size_t)(b * 2048 + qrow + qi) * 256 + h * 64 + g * 4;
    #pragma unroll
    for (int dt = 0; dt < 4; ++dt) {
        fx4 r;
        r[0] = o[dt][0] * inv; r[1] = o[dt][1] * inv;
        r[2] = o[dt][2] * inv; r[3] = o[dt][3] * inv;
        *(fx4*)(op + dt * 16) = r;
    }
}

// ---------------------------------------------------------------------------
// Launch
// ---------------------------------------------------------------------------
extern "C" void kernel_launch(void* const* d_in, const int* in_sizes, int n_in,
                              void* d_out, int out_size, void* d_ws, size_t ws_size,
                              hipStream_t stream) {
    const float* x      = (const float*)d_in[0];
    const int*   mask   = (const int*)  d_in[1];
    const float* bn1_g  = (const float*)d_in[2];
    const float* bn1_b  = (const float*)d_in[3];
    const float* bn1_m  = (const float*)d_in[4];
    const float* bn1_v  = (const float*)d_in[5];
    const float* qkv_w  = (const float*)d_in[6];
    const float* proj_w = (const float*)d_in[7];
    const float* bn2_g  = (const float*)d_in[8];
    const float* bn2_b  = (const float*)d_in[9];
    const float* bn2_m  = (const float*)d_in[10];
    const float* bn2_v  = (const float*)d_in[11];
    const float* w1     = (const float*)d_in[12];
    const float* w2     = (const float*)d_in[13];
    float* out = (float*)d_out;

    // workspace layout (bytes):
    //   [0,        4096)       bnc (4x256 f32)
    //   [4096,     8392704)    x2   (8192x256 f32)           live to end
    //   [8392704,  16781312)   qkvb (8192x512 bf16)          dead after attn
    //   [16781312, 20975616)   vt   (16x64x2048 bf16)        dead after attn
    //   [20975616, 29364224)   obuf (8192x256 f32)           dead after proj
    //   [8392704,  41947136)   h2   (8192x1024 f32)          overlays qkvb/vt/obuf
    char* w8 = (char*)d_ws;
    float*          bnc  = (float*)(w8);
    float*          x2   = (float*)(w8 + 4096);
    unsigned short* qkvb = (unsigned short*)(w8 + 8392704);
    unsigned short* vt   = (unsigned short*)(w8 + 16781312);
    float*          obuf = (float*)(w8 + 20975616);
    float*          h2   = (float*)(w8 + 8392704);

    const int M = B_ * S_;  // 8192

    bn_coef_k<<<1, 256, 0, stream>>>(bn1_g, bn1_b, bn1_m, bn1_v,
                                     bn2_g, bn2_b, bn2_m, bn2_v, bnc);

    // qkv = BN1(x) @ qkv_w -> qkvb (bf16, q scaled) + vt (V^T bf16)
    gemm_k<1, 3><<<dim3(768 / 64, M / 64), 256, 0, stream>>>(
        x, qkv_w, nullptr, nullptr, M, 768, 256, bnc, bnc + 256, qkvb, vt);

    // attention -> obuf (fp32 [B*S][256])
    attn_mfma_k<<<dim3(S_ / 64, H_, B_), 256, 0, stream>>>(qkvb, vt, mask, obuf);

    // x2 = obuf @ proj_w + x
    gemm_k<0, 1><<<dim3(256 / 64, M / 64), 256, 0, stream>>>(
        obuf, proj_w, x, x2, M, 256, 256, nullptr, nullptr, nullptr, nullptr);

    // h2 = swish(BN2(x2) @ w1)
    gemm_k<1, 2><<<dim3(1024 / 64, M / 64), 256, 0, stream>>>(
        x2, w1, nullptr, h2, M, 1024, 256, bnc + 512, bnc + 768, nullptr, nullptr);

    // out = h2 @ w2 + x2
    gemm_k<0, 1><<<dim3(256 / 64, M / 64), 256, 0, stream>>>(
        h2, w2, x2, out, M, 256, 1024, nullptr, nullptr, nullptr, nullptr);
}

// Round 3
// 200.410 us; speedup vs baseline: 12.4852x; 2.1867x over previous
//
#include <hip/hip_runtime.h>
#include <math.h>

// Problem constants
#define S_ 2048
#define D_ 256
#define B_ 4
#define H_ 4
// M = B*S = 8192, DH = 64

typedef __attribute__((ext_vector_type(8))) short  bh8;   // 8 bf16 (4 VGPR)
typedef __attribute__((ext_vector_type(4))) float  fx4;
typedef __attribute__((ext_vector_type(4))) int    ix4;
typedef __attribute__((ext_vector_type(4))) unsigned short us4;
typedef __attribute__((ext_vector_type(4))) unsigned int   ux4;

__device__ inline unsigned short bf16r(float f) {
    unsigned int u = __builtin_bit_cast(unsigned int, f);
    return (unsigned short)((u + 0x7FFFu + ((u >> 16) & 1u)) >> 16);
}
__device__ inline unsigned int pk2(float a, float b) {
    unsigned int ua = __builtin_bit_cast(unsigned int, a);
    unsigned int ub = __builtin_bit_cast(unsigned int, b);
    return ((ua + 0x8000u) >> 16) | ((ub + 0x8000u) & 0xFFFF0000u);
}
__device__ inline void gl_lds16(const unsigned short* g, unsigned short* l) {
    __builtin_amdgcn_global_load_lds(
        (const __attribute__((address_space(1))) unsigned int*)g,
        (__attribute__((address_space(3))) unsigned int*)l, 16, 0, 0);
}

// ---------------------------------------------------------------------------
// Weight prep: fp32 [K][N] -> bf16 [N][K] (transposed) for all 4 weights.
// unit = (k4, n): reads 4 rows of W at col n, writes us4 along k.
// ---------------------------------------------------------------------------
__global__ __launch_bounds__(256) void prep_w_k(
    const float* __restrict__ qkv_w, const float* __restrict__ proj_w,
    const float* __restrict__ w1,    const float* __restrict__ w2,
    unsigned short* __restrict__ qkv_wt, unsigned short* __restrict__ proj_wt,
    unsigned short* __restrict__ w1t,    unsigned short* __restrict__ w2t)
{
    const int bidx = blockIdx.x;
    const float* W; unsigned short* Wt; int K, N, u0;
    if (bidx < 192)      { W = qkv_w;  Wt = qkv_wt;  K = 256;  N = 768;  u0 = bidx * 256; }
    else if (bidx < 256) { W = proj_w; Wt = proj_wt; K = 256;  N = 256;  u0 = (bidx - 192) * 256; }
    else if (bidx < 512) { W = w1;     Wt = w1t;     K = 256;  N = 1024; u0 = (bidx - 256) * 256; }
    else                 { W = w2;     Wt = w2t;     K = 1024; N = 256;  u0 = (bidx - 512) * 256; }
    const int u = u0 + threadIdx.x;
    const int k4 = u / N, n = u % N;
    us4 tv;
    #pragma unroll
    for (int j = 0; j < 4; ++j) tv[j] = bf16r(W[(size_t)(k4 * 4 + j) * N + n]);
    *(us4*)&Wt[(size_t)n * K + k4 * 4] = tv;
}

// ---------------------------------------------------------------------------
// x prep: xb = bf16(BN1(x)), [8192][256]
// ---------------------------------------------------------------------------
__global__ __launch_bounds__(256) void prep_x_k(
    const float* __restrict__ x,
    const float* __restrict__ g1, const float* __restrict__ b1,
    const float* __restrict__ m1, const float* __restrict__ v1,
    unsigned short* __restrict__ xb)
{
    const int i = blockIdx.x * 256 + threadIdx.x;   // us4 unit
    const int c4 = (i & 63) * 4;
    float4 xv = *(const float4*)&x[(size_t)i * 4];
    float vv[4] = {xv.x, xv.y, xv.z, xv.w};
    us4 tv;
    #pragma unroll
    for (int j = 0; j < 4; ++j) {
        int c = c4 + j;
        float s = g1[c] * rsqrtf(v1[c] + 1e-3f);
        tv[j] = bf16r(vv[j] * s + (b1[c] - m1[c] * s));
    }
    *(us4*)&xb[(size_t)i * 4] = tv;
}

// ---------------------------------------------------------------------------
// MFMA GEMM: C = A[M][K](bf16) x Wt[N][K](bf16), fp32 accum. Tile BMx128,
// BK=32, 4 waves (2x2, each BM/2 x 64). global_load_lds staging, m97-style.
// E=0: qkv epilogue (qkvb bf16 [m][512] with q*1/16, vt bf16 [BH][64][2048])
// E=1: proj: outf = acc + res (x2 f32), outb = bf16(BN2(outf))
// E=2: mlp1: outb = bf16(swish(acc))
// E=3: mlp2: outf = acc + res
// ---------------------------------------------------------------------------
template<int BM, int E>
__global__ __launch_bounds__(256) void gemm_mfma_k(
    const unsigned short* __restrict__ A, const unsigned short* __restrict__ Wt,
    int N, int K,
    const float* __restrict__ res, float* __restrict__ outf,
    unsigned short* __restrict__ outb, unsigned short* __restrict__ vt,
    const float* __restrict__ g2, const float* __restrict__ b2,
    const float* __restrict__ m2, const float* __restrict__ v2)
{
    constexpr int MI = BM / 32;
    __shared__ unsigned short Asb[BM * 32];
    __shared__ unsigned short Bsb[128 * 32];
    const int n0 = blockIdx.x * 128, m0 = blockIdx.y * BM;
    const int t = threadIdx.x, w = t >> 6, l = t & 63;
    const int qi = l & 15, g = l >> 4;
    const int wm = w >> 1, wn = w & 1;

    fx4 acc[MI][4];
    #pragma unroll
    for (int mi = 0; mi < MI; ++mi)
        #pragma unroll
        for (int ni = 0; ni < 4; ++ni) acc[mi][ni] = (fx4){0.f, 0.f, 0.f, 0.f};

    for (int k0 = 0; k0 < K; k0 += 32) {
        __syncthreads();
        #pragma unroll
        for (int i = 0; i < BM / 64; ++i) {
            int r0 = (w * (BM / 64) + i) * 16;
            gl_lds16(A + (size_t)(m0 + r0 + (l >> 2)) * K + k0 + 8 * (l & 3),
                     &Asb[r0 * 32]);
        }
        #pragma unroll
        for (int i = 0; i < 2; ++i) {
            int r0 = (w * 2 + i) * 16;
            gl_lds16(Wt + (size_t)(n0 + r0 + (l >> 2)) * K + k0 + 8 * (l & 3),
                     &Bsb[r0 * 32]);
        }
        __syncthreads();
        bh8 af[MI], bf[4];
        #pragma unroll
        for (int mi = 0; mi < MI; ++mi)
            af[mi] = *(const bh8*)&Asb[(wm * (BM / 2) + mi * 16 + qi) * 32 + g * 8];
        #pragma unroll
        for (int ni = 0; ni < 4; ++ni)
            bf[ni] = *(const bh8*)&Bsb[(wn * 64 + ni * 16 + qi) * 32 + g * 8];
        #pragma unroll
        for (int mi = 0; mi < MI; ++mi)
            #pragma unroll
            for (int ni = 0; ni < 4; ++ni)
                acc[mi][ni] = __builtin_amdgcn_mfma_f32_16x16x32_bf16(
                    af[mi], bf[ni], acc[mi][ni], 0, 0, 0);
    }

    const int mbase = m0 + wm * (BM / 2);
    #pragma unroll
    for (int ni = 0; ni < 4; ++ni) {
        const int nf = n0 + wn * 64 + ni * 16;
        if (E == 0) {
            const int h = nf / 192, rem = nf % 192;
            const int region = rem / 64, c = rem % 64 + qi;
            #pragma unroll
            for (int mi = 0; mi < MI; ++mi) {
                #pragma unroll
                for (int r = 0; r < 4; ++r) {
                    const int m = mbase + mi * 16 + g * 4 + r;
                    float a = acc[mi][ni][r];
                    if (region < 2) {
                        outb[(size_t)m * 512 + h * 128 + region * 64 + c] =
                            bf16r(region == 0 ? a * 0.0625f : a);
                    } else {
                        vt[(((size_t)(m >> 11) * 4 + h) * 64 + c) * 2048 + (m & 2047)] =
                            bf16r(a);
                    }
                }
            }
        } else if (E == 1) {
            const int n = nf + qi;
            const float s2 = g2[n] * rsqrtf(v2[n] + 1e-3f);
            const float o2 = b2[n] - m2[n] * s2;
            #pragma unroll
            for (int mi = 0; mi < MI; ++mi) {
                #pragma unroll
                for (int r = 0; r < 4; ++r) {
                    const int m = mbase + mi * 16 + g * 4 + r;
                    const size_t idx = (size_t)m * N + n;
                    float rv = acc[mi][ni][r] + res[idx];
                    outf[idx] = rv;
                    outb[idx] = bf16r(rv * s2 + o2);
                }
            }
        } else if (E == 2) {
            const int n = nf + qi;
            #pragma unroll
            for (int mi = 0; mi < MI; ++mi) {
                #pragma unroll
                for (int r = 0; r < 4; ++r) {
                    const int m = mbase + mi * 16 + g * 4 + r;
                    float a = acc[mi][ni][r];
                    outb[(size_t)m * N + n] = bf16r(a / (1.0f + __expf(-a)));
                }
            }
        } else {
            const int n = nf + qi;
            #pragma unroll
            for (int mi = 0; mi < MI; ++mi) {
                #pragma unroll
                for (int r = 0; r < 4; ++r) {
                    const int m = mbase + mi * 16 + g * 4 + r;
                    const size_t idx = (size_t)m * N + n;
                    outf[idx] = acc[mi][ni][r] + res[idx];
                }
            }
        }
    }
}

// ---------------------------------------------------------------------------
// MFMA flash attention with register double-buffer prefetch, bf16 out.
// Block = 4 waves; wave owns 16 q-rows. Grid (S/64, H, B).
// ---------------------------------------------------------------------------
__global__ __launch_bounds__(256) void attn_mfma_k(
    const unsigned short* __restrict__ qkvb,
    const unsigned short* __restrict__ vt,
    const int* __restrict__ mask,
    unsigned short* __restrict__ ob)
{
    const int b = blockIdx.z, h = blockIdx.y;
    const int t = threadIdx.x;
    const int w = t >> 6, lane = t & 63;
    const int g = lane >> 4, qi = lane & 15;
    const int qrow = blockIdx.x * 64 + w * 16;

    bh8 qf0, qf1;
    {
        const unsigned short* qp =
            qkvb + (size_t)(b * 2048 + qrow + qi) * 512 + h * 128 + g * 8;
        qf0 = *(const bh8*)(qp);
        qf1 = *(const bh8*)(qp + 32);
    }

    fx4 o[4];
    #pragma unroll
    for (int dt = 0; dt < 4; ++dt) o[dt] = (fx4){0.f, 0.f, 0.f, 0.f};
    float m_r = -1e30f, l_r = 0.f;

    const unsigned short* kbase =
        qkvb + (size_t)(b * 2048) * 512 + h * 128 + 64 + g * 8;
    const unsigned short* vb0 =
        vt + ((size_t)((b * 4 + h) * 64 + qi)) * 2048 + g * 8;
    const int* mbase = mask + b * 2048 + g * 4;

    bh8 kfA[4][2], kfB[4][2], afA[4][2], afB[4][2];
    ix4 mvA[4], mvB[4];

#define LOADK(KF, MV, K64) {                                                  \
    _Pragma("unroll")                                                         \
    for (int kt = 0; kt < 4; ++kt) {                                          \
        const unsigned short* kp = kbase + (size_t)((K64) + kt * 16 + qi) * 512; \
        KF[kt][0] = *(const bh8*)(kp);                                        \
        KF[kt][1] = *(const bh8*)(kp + 32);                                   \
        MV[kt] = *(const ix4*)(mbase + (K64) + kt * 16);                      \
    } }

#define LOADV(AF, K64) {                                                      \
    _Pragma("unroll")                                                         \
    for (int dt = 0; dt < 4; ++dt) {                                          \
        const unsigned short* vp = vb0 + (size_t)dt * 16 * 2048 + (K64);      \
        AF[dt][0] = *(const bh8*)(vp);                                        \
        AF[dt][1] = *(const bh8*)(vp + 32);                                   \
    } }

#define PROCESS(KF, AF, MV) {                                                 \
    fx4 s[4];                                                                 \
    _Pragma("unroll")                                                         \
    for (int kt = 0; kt < 4; ++kt) {                                          \
        fx4 z = (fx4){0.f, 0.f, 0.f, 0.f};                                    \
        z = __builtin_amdgcn_mfma_f32_16x16x32_bf16(KF[kt][0], qf0, z, 0, 0, 0); \
        z = __builtin_amdgcn_mfma_f32_16x16x32_bf16(KF[kt][1], qf1, z, 0, 0, 0); \
        s[kt] = z;                                                            \
    }                                                                         \
    float tmax = -1e30f;                                                      \
    _Pragma("unroll")                                                         \
    for (int kt = 0; kt < 4; ++kt) {                                          \
        _Pragma("unroll")                                                     \
        for (int r = 0; r < 4; ++r) {                                         \
            float sv = s[kt][r] + (MV[kt][r] ? 0.0f : -1e9f);                 \
            s[kt][r] = sv;                                                    \
            tmax = fmaxf(tmax, sv);                                           \
        }                                                                     \
    }                                                                         \
    tmax = fmaxf(tmax, __shfl_xor(tmax, 16, 64));                             \
    tmax = fmaxf(tmax, __shfl_xor(tmax, 32, 64));                             \
    float mnew = fmaxf(m_r, tmax);                                            \
    float fac = __expf(m_r - mnew);                                           \
    float psum = 0.f;                                                         \
    unsigned int pkv[4][2];                                                   \
    _Pragma("unroll")                                                         \
    for (int kt = 0; kt < 4; ++kt) {                                          \
        float p0 = __expf(s[kt][0] - mnew);                                   \
        float p1 = __expf(s[kt][1] - mnew);                                   \
        float p2 = __expf(s[kt][2] - mnew);                                   \
        float p3 = __expf(s[kt][3] - mnew);                                   \
        psum += (p0 + p1) + (p2 + p3);                                        \
        pkv[kt][0] = pk2(p0, p1);                                             \
        pkv[kt][1] = pk2(p2, p3);                                             \
    }                                                                         \
    psum += __shfl_xor(psum, 16, 64);                                         \
    psum += __shfl_xor(psum, 32, 64);                                         \
    l_r = l_r * fac + psum;                                                   \
    m_r = mnew;                                                               \
    _Pragma("unroll")                                                         \
    for (int dt = 0; dt < 4; ++dt) {                                          \
        o[dt][0] *= fac; o[dt][1] *= fac; o[dt][2] *= fac; o[dt][3] *= fac;   \
    }                                                                         \
    _Pragma("unroll")                                                         \
    for (int c = 0; c < 2; ++c) {                                             \
        unsigned int bw[4];                                                   \
        _Pragma("unroll")                                                     \
        for (int wd = 0; wd < 4; ++wd) {                                      \
            int src = (2 * (g & 1) + (wd >> 1)) * 16 + qi;                    \
            unsigned int va = (unsigned int)__shfl((int)pkv[2 * c][wd & 1], src, 64);     \
            unsigned int vb = (unsigned int)__shfl((int)pkv[2 * c + 1][wd & 1], src, 64); \
            bw[wd] = (g >= 2) ? vb : va;                                      \
        }                                                                     \
        ux4 bwv = (ux4){bw[0], bw[1], bw[2], bw[3]};                          \
        bh8 bfrag = __builtin_bit_cast(bh8, bwv);                             \
        _Pragma("unroll")                                                     \
        for (int dt = 0; dt < 4; ++dt)                                        \
            o[dt] = __builtin_amdgcn_mfma_f32_16x16x32_bf16(                  \
                AF[dt][c], bfrag, o[dt], 0, 0, 0);                            \
    } }

    LOADK(kfA, mvA, 0);
    LOADV(afA, 0);
    for (int k64 = 0; k64 < 2048; k64 += 128) {
        LOADK(kfB, mvB, k64 + 64);
        LOADV(afB, k64 + 64);
        PROCESS(kfA, afA, mvA);
        if (k64 + 128 < 2048) {
            LOADK(kfA, mvA, k64 + 128);
            LOADV(afA, k64 + 128);
        }
        PROCESS(kfB, afB, mvB);
    }
#undef LOADK
#undef LOADV
#undef PROCESS

    float inv = 1.0f / l_r;
    unsigned short* op = ob + (size_t)(b * 2048 + qrow + qi) * 256 + h * 64 + g * 4;
    #pragma unroll
    for (int dt = 0; dt < 4; ++dt) {
        us4 tv;
        #pragma unroll
        for (int r = 0; r < 4; ++r) tv[r] = bf16r(o[dt][r] * inv);
        *(us4*)(op + dt * 16) = tv;
    }
}

// ---------------------------------------------------------------------------
// Launch
// ---------------------------------------------------------------------------
extern "C" void kernel_launch(void* const* d_in, const int* in_sizes, int n_in,
                              void* d_out, int out_size, void* d_ws, size_t ws_size,
                              hipStream_t stream) {
    const float* x      = (const float*)d_in[0];
    const int*   mask   = (const int*)  d_in[1];
    const float* bn1_g  = (const float*)d_in[2];
    const float* bn1_b  = (const float*)d_in[3];
    const float* bn1_m  = (const float*)d_in[4];
    const float* bn1_v  = (const float*)d_in[5];
    const float* qkv_w  = (const float*)d_in[6];
    const float* proj_w = (const float*)d_in[7];
    const float* bn2_g  = (const float*)d_in[8];
    const float* bn2_b  = (const float*)d_in[9];
    const float* bn2_m  = (const float*)d_in[10];
    const float* bn2_v  = (const float*)d_in[11];
    const float* w1     = (const float*)d_in[12];
    const float* w2     = (const float*)d_in[13];
    float* out = (float*)d_out;

    // workspace layout (bytes)
    char* w8 = (char*)d_ws;
    unsigned short* qkv_wt  = (unsigned short*)(w8 + 0);         // 384 KB
    unsigned short* proj_wt = (unsigned short*)(w8 + 393216);    // 128 KB
    unsigned short* w1t     = (unsigned short*)(w8 + 524288);    // 512 KB
    unsigned short* w2t     = (unsigned short*)(w8 + 1048576);   // 512 KB
    unsigned short* xb      = (unsigned short*)(w8 + 2097152);   // 4 MB
    float*          x2      = (float*)         (w8 + 6291456);   // 8 MB
    unsigned short* x2nb    = (unsigned short*)(w8 + 14680064);  // 4 MB
    unsigned short* qkvb    = (unsigned short*)(w8 + 18874368);  // 8 MB
    unsigned short* vt      = (unsigned short*)(w8 + 27262976);  // 4 MB
    unsigned short* ob      = (unsigned short*)(w8 + 31457280);  // 4 MB
    unsigned short* h2b     = (unsigned short*)(w8 + 18874368);  // 16 MB overlay

    // prep
    prep_w_k<<<768, 256, 0, stream>>>(qkv_w, proj_w, w1, w2,
                                      qkv_wt, proj_wt, w1t, w2t);
    prep_x_k<<<2048, 256, 0, stream>>>(x, bn1_g, bn1_b, bn1_m, bn1_v, xb);

    // qkv = xb @ qkv_wt -> qkvb + vt
    gemm_mfma_k<128, 0><<<dim3(6, 64), 256, 0, stream>>>(
        xb, qkv_wt, 768, 256, nullptr, nullptr, qkvb, vt,
        nullptr, nullptr, nullptr, nullptr);

    // attention -> ob (bf16)
    attn_mfma_k<<<dim3(S_ / 64, H_, B_), 256, 0, stream>>>(qkvb, vt, mask, ob);

    // x2 = ob @ proj_wt + x ; x2nb = bf16(BN2(x2))
    gemm_mfma_k<64, 1><<<dim3(2, 128), 256, 0, stream>>>(
        ob, proj_wt, 256, 256, x, x2, x2nb, nullptr,
        bn2_g, bn2_b, bn2_m, bn2_v);

    // h2b = bf16(swish(x2nb @ w1t))
    gemm_mfma_k<128, 2><<<dim3(8, 64), 256, 0, stream>>>(
        x2nb, w1t, 1024, 256, nullptr, nullptr, h2b, nullptr,
        nullptr, nullptr, nullptr, nullptr);

    // out = h2b @ w2t + x2
    gemm_mfma_k<64, 3><<<dim3(2, 128), 256, 0, stream>>>(
        h2b, w2t, 256, 1024, x2, out, nullptr, nullptr,
        nullptr, nullptr, nullptr, nullptr);
}